// Round 1
// baseline (159.945 us; speedup 1.0000x reference)
//
#include <hip/hip_runtime.h>
#include <hip/hip_bf16.h>

// Colorcal: out[b,c,h,w] = (wcam[cam[b],c] + wident[id[b],c]) * image[b,c,h,w]
//                        + (bcam[cam[b],c] + bident[id[b],c])
// B=32, C=3, H=W=1024, all fp32. Pure streaming op -> HBM roofline ~128us.

#define HW (1024 * 1024)
#define HW4 (HW / 4)

__global__ __launch_bounds__(256) void colorcal_kernel(
    const float* __restrict__ image,
    const int*   __restrict__ camindex,
    const int*   __restrict__ idindex,
    const float* __restrict__ wcam,
    const float* __restrict__ bcam,
    const float* __restrict__ wident,
    const float* __restrict__ bident,
    float* __restrict__ out)
{
    const int plane = blockIdx.y;          // 0..95  == b*3 + c
    const int b     = plane / 3;
    const int c     = plane - b * 3;

    // Wave-uniform scalar gathers: one per block, broadcast via L1.
    const int cam = camindex[b];
    const int id  = idindex[b];
    const float w    = wcam[cam * 3 + c] + wident[id * 3 + c];
    const float bias = bcam[cam * 3 + c] + bident[id * 3 + c];

    const size_t planeBase = (size_t)plane * HW;
    const float4* __restrict__ in4  = reinterpret_cast<const float4*>(image + planeBase);
    float4*       __restrict__ out4 = reinterpret_cast<float4*>(out + planeBase);

    const int stride = gridDim.x * blockDim.x;
    for (int i = blockIdx.x * blockDim.x + threadIdx.x; i < HW4; i += stride) {
        float4 v = in4[i];
        v.x = fmaf(w, v.x, bias);
        v.y = fmaf(w, v.y, bias);
        v.z = fmaf(w, v.z, bias);
        v.w = fmaf(w, v.w, bias);
        out4[i] = v;
    }
}

extern "C" void kernel_launch(void* const* d_in, const int* in_sizes, int n_in,
                              void* d_out, int out_size, void* d_ws, size_t ws_size,
                              hipStream_t stream) {
    const float* image    = (const float*)d_in[0];
    const int*   camindex = (const int*)  d_in[1];
    const int*   idindex  = (const int*)  d_in[2];
    const float* wcam     = (const float*)d_in[3];
    const float* bcam     = (const float*)d_in[4];
    const float* wident   = (const float*)d_in[5];
    const float* bident   = (const float*)d_in[6];
    float* out = (float*)d_out;

    // 96 planes (B*C); 128 blocks x 256 threads per plane, float4 grid-stride.
    dim3 grid(128, 96, 1);
    dim3 block(256, 1, 1);
    colorcal_kernel<<<grid, block, 0, stream>>>(
        image, camindex, idindex, wcam, bcam, wident, bident, out);
}